// Round 1
// baseline (732.014 us; speedup 1.0000x reference)
//
#include <hip/hip_runtime.h>
#include <math.h>

// Problem constants (match reference)
#define K_NN   16
#define BATCH  2
#define NA     16384
#define NB     8192
#define CH     128
#define TILE   2048
#define WAVES_PER_BLOCK 4

__global__ __launch_bounds__(256, 2) void knn_agg_kernel(
    const float* __restrict__ tfeat,   // [B, NA, C]
    const float* __restrict__ tpos,    // [B, NA, 3]
    const float* __restrict__ spos,    // [B, NB, 3]
    float* __restrict__ out)           // [B, NB, C]
{
    __shared__ float4 sP[TILE];        // 32 KiB

    const int tid  = threadIdx.x;
    const int lane = tid & 63;
    const int wave = tid >> 6;

    const int blocks_per_batch = NB / WAVES_PER_BLOCK;     // 2048
    const int b = blockIdx.x / blocks_per_batch;
    const int n = (blockIdx.x % blocks_per_batch) * WAVES_PER_BLOCK + wave;

    const float INF = __builtin_inff();

    const float* tp = tpos + (size_t)b * NA * 3;
    const float* sp = spos + ((size_t)b * NB + n) * 3;
    const float sx = sp[0], sy = sp[1], sz = sp[2];

    // per-lane running top-16 (statically indexed registers only)
    float dlist[K_NN];
    int   ilist[K_NN];
#pragma unroll
    for (int j = 0; j < K_NN; ++j) { dlist[j] = INF; ilist[j] = -1; }
    float curmax  = INF;
    int   maxslot = 0;

    for (int t = 0; t < NA; t += TILE) {
        __syncthreads();
        // cooperative stage of TILE teacher positions into LDS
        for (int j = tid; j < TILE; j += 256) {
            const float* p = tp + (size_t)(t + j) * 3;
            sP[j] = make_float4(p[0], p[1], p[2], 0.f);
        }
        __syncthreads();

        for (int i = 0; i < TILE / 64; ++i) {
            const int s = i * 64 + lane;
            const float4 p = sP[s];
            const float dx = sx - p.x;
            const float dy = sy - p.y;
            const float dz = sz - p.z;
            const float d2 = dx * dx + dy * dy + dz * dz;
            if (d2 < curmax) {
                // replace current argmax slot (static-index selects)
#pragma unroll
                for (int j = 0; j < K_NN; ++j) {
                    if (j == maxslot) { dlist[j] = d2; ilist[j] = t + s; }
                }
                // rescan for new max + argmax
                float m = dlist[0]; int ms = 0;
#pragma unroll
                for (int j = 1; j < K_NN; ++j) {
                    if (dlist[j] > m) { m = dlist[j]; ms = j; }
                }
                curmax = m; maxslot = ms;
            }
        }
    }

    // ---- wave-wide merge: extract global 16 smallest from 64 lane-lists ----
    float selD[K_NN];
    int   selI[K_NN];
#pragma unroll
    for (int r = 0; r < K_NN; ++r) {
        // per-lane min (track value, slot, candidate index statically)
        float m = dlist[0]; int slot = 0; int cbest = ilist[0];
#pragma unroll
        for (int j = 1; j < K_NN; ++j) {
            if (dlist[j] < m) { m = dlist[j]; slot = j; cbest = ilist[j]; }
        }
        // wave argmin reduce (value, candidate-id payload; id tiebreak)
        float v = m; int c = cbest;
#pragma unroll
        for (int off = 32; off > 0; off >>= 1) {
            const float ov = __shfl_xor(v, off);
            const int   oc = __shfl_xor(c, off);
            if (ov < v || (ov == v && oc < c)) { v = ov; c = oc; }
        }
        selD[r] = v; selI[r] = c;
        // winning lane retires its slot
        const bool win = (m == v) && (cbest == c);
#pragma unroll
        for (int j = 0; j < K_NN; ++j) {
            if (win && j == slot) dlist[j] = INF;
        }
    }

    // ---- weights + normalized feature aggregation ----
    float w[K_NN];
    float wsum = 0.f;
#pragma unroll
    for (int r = 0; r < K_NN; ++r) {
        w[r] = expf(-0.5f * selD[r]);
        wsum += w[r];
    }
    const float inv = 1.0f / wsum;

    const float* fb = tfeat + (size_t)b * NA * CH;
    float acc0 = 0.f, acc1 = 0.f;
#pragma unroll
    for (int r = 0; r < K_NN; ++r) {
        const float* f = fb + (size_t)selI[r] * CH;
        const float ww = w[r] * inv;
        acc0 += ww * f[lane];
        acc1 += ww * f[lane + 64];
    }

    float* o = out + ((size_t)b * NB + n) * CH;
    o[lane]      = acc0;
    o[lane + 64] = acc1;
}

extern "C" void kernel_launch(void* const* d_in, const int* in_sizes, int n_in,
                              void* d_out, int out_size, void* d_ws, size_t ws_size,
                              hipStream_t stream) {
    const float* tfeat = (const float*)d_in[0];   // [B,NA,C]
    const float* tpos  = (const float*)d_in[1];   // [B,NA,3]
    const float* spos  = (const float*)d_in[2];   // [B,NB,3]
    float* out = (float*)d_out;                   // [B,NB,C]

    const int blocks = BATCH * (NB / WAVES_PER_BLOCK);    // 4096
    knn_agg_kernel<<<blocks, 256, 0, stream>>>(tfeat, tpos, spos, out);
}

// Round 3
// 192.776 us; speedup vs baseline: 3.7972x; 3.7972x over previous
//
#include <hip/hip_runtime.h>
#include <math.h>

#define K_NN   16
#define BATCH  2
#define NA_    16384
#define NB_    8192
#define CH     128
// coords are [z,y,x]: z in [0,64), y in [0,256), x in [0,256); cell edge 16
#define CZ     4
#define CY     16
#define CX     16
#define NCELL  (CZ*CY*CX)   // 1024
#define CSH    4

// ---------------- grid build kernels ----------------

__device__ __forceinline__ int cell_of(float p0, float p1, float p2) {
    const int cz = ((int)p0) >> CSH;   // z / 16  in [0,4)
    const int cy = ((int)p1) >> CSH;   // y / 16  in [0,16)
    const int cx = ((int)p2) >> CSH;   // x / 16  in [0,16)
    return (cz * CY + cy) * CX + cx;
}

__global__ void count_kernel(const float* __restrict__ tpos, int* __restrict__ counts) {
    int i = blockIdx.x * 256 + threadIdx.x;            // over B*NA
    if (i >= BATCH * NA_) return;
    int b = i / NA_;
    const float* tp = tpos + (size_t)i * 3;
    atomicAdd(&counts[b * NCELL + cell_of(tp[0], tp[1], tp[2])], 1);
}

__global__ void scan_kernel(const int* __restrict__ counts,
                            int2* __restrict__ meta, int* __restrict__ cursor) {
    __shared__ int s[NCELL];
    const int b = blockIdx.x, t = threadIdx.x;
    int c = counts[b * NCELL + t];
    s[t] = c;
    __syncthreads();
    for (int off = 1; off < NCELL; off <<= 1) {
        int u = (t >= off) ? s[t - off] : 0;
        __syncthreads();
        s[t] += u;
        __syncthreads();
    }
    int excl = s[t] - c;
    meta[b * NCELL + t]   = make_int2(excl, c);
    cursor[b * NCELL + t] = excl;
}

__global__ void scatter_kernel(const float* __restrict__ tpos,
                               int* __restrict__ cursor, float4* __restrict__ sorted) {
    int i = blockIdx.x * 256 + threadIdx.x;            // over B*NA
    if (i >= BATCH * NA_) return;
    int b = i / NA_, p = i % NA_;
    const float* tp = tpos + (size_t)i * 3;
    float p0 = tp[0], p1 = tp[1], p2 = tp[2];
    int cell = cell_of(p0, p1, p2);
    int pos = atomicAdd(&cursor[b * NCELL + cell], 1);
    sorted[(size_t)b * NA_ + pos] = make_float4(p0, p1, p2, __int_as_float(p));
}

// ---------------- main KNN + aggregation ----------------

__global__ __launch_bounds__(256) void knn_cells_kernel(
    const float* __restrict__ tfeat,   // [B, NA, C]
    const float* __restrict__ spos,    // [B, NB, 3]
    const int2*  __restrict__ meta,    // [B, NCELL] (start, count)
    const float4* __restrict__ sorted, // [B, NA]
    float* __restrict__ out)           // [B, NB, C]
{
    const int tid  = threadIdx.x;
    const int lane = tid & 63;
    const int wave = tid >> 6;

    const int blocks_per_batch = NB_ / 4;
    const int b = blockIdx.x / blocks_per_batch;
    const int n = (blockIdx.x % blocks_per_batch) * 4 + wave;

    const float INF = __builtin_inff();

    const float* sp = spos + ((size_t)b * NB_ + n) * 3;
    const float s0 = sp[0], s1 = sp[1], s2 = sp[2];   // z, y, x
    const int scz = ((int)s0) >> CSH;                  // [0,4)
    const int scy = ((int)s1) >> CSH;                  // [0,16)
    const int scx = ((int)s2) >> CSH;                  // [0,16)

    int rcov = max(max(scx, CX - 1 - scx), max(scy, CY - 1 - scy));
    rcov = max(rcov, max(scz, CZ - 1 - scz));

    const int2*   mb = meta   + (size_t)b * NCELL;
    const float4* sb = sorted + (size_t)b * NA_;

    float dlist[K_NN];
    int   ilist[K_NN];
    float selD[K_NN];
    int   selI[K_NN];
    bool have_prev = false;

    for (int r = 1;; ++r) {
#pragma unroll
        for (int j = 0; j < K_NN; ++j) { dlist[j] = INF; ilist[j] = -1; }
        float curmax = INF;
        int   maxslot = 0;

        auto ins = [&](float d2v, int idxv) {
            if (d2v < curmax) {
#pragma unroll
                for (int j = 0; j < K_NN; ++j)
                    if (j == maxslot) { dlist[j] = d2v; ilist[j] = idxv; }
                float mm = dlist[0]; int ms = 0;
#pragma unroll
                for (int j = 1; j < K_NN; ++j)
                    if (dlist[j] > mm) { mm = dlist[j]; ms = j; }
                curmax = mm; maxslot = ms;
            }
        };

        // seed previous selection (lane j carries prev result j; values wave-uniform)
        if (have_prev) {
            float sd = INF; int si = -1;
#pragma unroll
            for (int j = 0; j < K_NN; ++j)
                if (lane == j) { sd = selD[j]; si = selI[j]; }
            ins(sd, si);
        }

        // iterate cells: first pass = full box r<=1, later passes = shell chebyshev==r
        for (int dz = -r; dz <= r; ++dz) {
            int cz = scz + dz; if ((unsigned)cz >= CZ) continue;
            for (int dy = -r; dy <= r; ++dy) {
                int cy = scy + dy; if ((unsigned)cy >= CY) continue;
                for (int dx = -r; dx <= r; ++dx) {
                    int cx = scx + dx; if ((unsigned)cx >= CX) continue;
                    if (r > 1) {
                        int ch = max(abs(dz), max(abs(dy), abs(dx)));
                        if (ch < r) continue;
                    }
                    const int2 m = mb[(cz * CY + cy) * CX + cx];
                    for (int o = 0; o < m.y; o += 64) {
                        const int j = o + lane;
                        const bool active = j < m.y;
                        float4 p = active ? sb[m.x + j]
                                          : make_float4(0.f, 0.f, 0.f, __int_as_float(-1));
                        const float d0 = s0 - p.x;
                        const float d1 = s1 - p.y;
                        const float d2c = s2 - p.z;
                        float d2 = d0 * d0 + d1 * d1 + d2c * d2c;
                        d2 = active ? d2 : INF;
                        ins(d2, __float_as_int(p.w));
                    }
                }
            }
        }

        // ---- wave-wide merge: extract 16 smallest (sorted ascending) ----
#pragma unroll
        for (int rr = 0; rr < K_NN; ++rr) {
            float m = dlist[0]; int slot = 0; int cbest = ilist[0];
#pragma unroll
            for (int j = 1; j < K_NN; ++j)
                if (dlist[j] < m) { m = dlist[j]; slot = j; cbest = ilist[j]; }
            float v = m; int c = cbest;
#pragma unroll
            for (int off = 32; off > 0; off >>= 1) {
                const float ov = __shfl_xor(v, off);
                const int   oc = __shfl_xor(c, off);
                if (ov < v || (ov == v && oc < c)) { v = ov; c = oc; }
            }
            selD[rr] = v; selI[rr] = c;
            const bool win = (m == v) && (cbest == c);
#pragma unroll
            for (int j = 0; j < K_NN; ++j)
                if (win && j == slot) dlist[j] = INF;
        }

        have_prev = true;
        const float stopd = (float)(256 * r * r);   // (16r)^2
        if (selD[K_NN - 1] <= stopd || r >= rcov) break;
    }

    // ---- weights + normalized feature aggregation ----
    float w[K_NN];
    float wsum = 0.f;
#pragma unroll
    for (int rr = 0; rr < K_NN; ++rr) {
        w[rr] = expf(-0.5f * selD[rr]);
        wsum += w[rr];
    }
    const float inv = 1.0f / wsum;

    const float* fb = tfeat + (size_t)b * NA_ * CH;
    float acc0 = 0.f, acc1 = 0.f;
#pragma unroll
    for (int rr = 0; rr < K_NN; ++rr) {
        const float* f = fb + (size_t)selI[rr] * CH;
        const float ww = w[rr] * inv;
        acc0 += ww * f[lane];
        acc1 += ww * f[lane + 64];
    }

    float* o = out + ((size_t)b * NB_ + n) * CH;
    o[lane]      = acc0;
    o[lane + 64] = acc1;
}

// ---------------- brute-force fallback (if ws too small) ----------------

__global__ __launch_bounds__(256, 2) void knn_brute_kernel(
    const float* __restrict__ tfeat, const float* __restrict__ tpos,
    const float* __restrict__ spos, float* __restrict__ out)
{
    __shared__ float4 sP[2048];
    const int tid = threadIdx.x, lane = tid & 63, wave = tid >> 6;
    const int bpb = NB_ / 4;
    const int b = blockIdx.x / bpb;
    const int n = (blockIdx.x % bpb) * 4 + wave;
    const float INF = __builtin_inff();
    const float* tp = tpos + (size_t)b * NA_ * 3;
    const float* sp = spos + ((size_t)b * NB_ + n) * 3;
    const float sx = sp[0], sy = sp[1], sz = sp[2];
    float dlist[K_NN]; int ilist[K_NN];
#pragma unroll
    for (int j = 0; j < K_NN; ++j) { dlist[j] = INF; ilist[j] = -1; }
    float curmax = INF; int maxslot = 0;
    for (int t = 0; t < NA_; t += 2048) {
        __syncthreads();
        for (int j = tid; j < 2048; j += 256) {
            const float* p = tp + (size_t)(t + j) * 3;
            sP[j] = make_float4(p[0], p[1], p[2], 0.f);
        }
        __syncthreads();
        for (int i = 0; i < 2048 / 64; ++i) {
            const int s = i * 64 + lane;
            const float4 p = sP[s];
            const float dx = sx - p.x, dy = sy - p.y, dz = sz - p.z;
            const float d2 = dx * dx + dy * dy + dz * dz;
            if (d2 < curmax) {
#pragma unroll
                for (int j = 0; j < K_NN; ++j)
                    if (j == maxslot) { dlist[j] = d2; ilist[j] = t + s; }
                float m = dlist[0]; int ms = 0;
#pragma unroll
                for (int j = 1; j < K_NN; ++j)
                    if (dlist[j] > m) { m = dlist[j]; ms = j; }
                curmax = m; maxslot = ms;
            }
        }
    }
    float selD[K_NN]; int selI[K_NN];
#pragma unroll
    for (int r = 0; r < K_NN; ++r) {
        float m = dlist[0]; int slot = 0; int cbest = ilist[0];
#pragma unroll
        for (int j = 1; j < K_NN; ++j)
            if (dlist[j] < m) { m = dlist[j]; slot = j; cbest = ilist[j]; }
        float v = m; int c = cbest;
#pragma unroll
        for (int off = 32; off > 0; off >>= 1) {
            const float ov = __shfl_xor(v, off);
            const int oc = __shfl_xor(c, off);
            if (ov < v || (ov == v && oc < c)) { v = ov; c = oc; }
        }
        selD[r] = v; selI[r] = c;
        const bool win = (m == v) && (cbest == c);
#pragma unroll
        for (int j = 0; j < K_NN; ++j)
            if (win && j == slot) dlist[j] = INF;
    }
    float w[K_NN]; float wsum = 0.f;
#pragma unroll
    for (int r = 0; r < K_NN; ++r) { w[r] = expf(-0.5f * selD[r]); wsum += w[r]; }
    const float inv = 1.0f / wsum;
    const float* fb = tfeat + (size_t)b * NA_ * CH;
    float acc0 = 0.f, acc1 = 0.f;
#pragma unroll
    for (int r = 0; r < K_NN; ++r) {
        const float* f = fb + (size_t)selI[r] * CH;
        const float ww = w[r] * inv;
        acc0 += ww * f[lane];
        acc1 += ww * f[lane + 64];
    }
    float* o = out + ((size_t)b * NB_ + n) * CH;
    o[lane] = acc0; o[lane + 64] = acc1;
}

// ---------------- launch ----------------

extern "C" void kernel_launch(void* const* d_in, const int* in_sizes, int n_in,
                              void* d_out, int out_size, void* d_ws, size_t ws_size,
                              hipStream_t stream) {
    const float* tfeat = (const float*)d_in[0];   // [B,NA,C]
    const float* tpos  = (const float*)d_in[1];   // [B,NA,3]
    const float* spos  = (const float*)d_in[2];   // [B,NB,3]
    float* out = (float*)d_out;                   // [B,NB,C]

    const size_t OFF_COUNTS = 0;
    const size_t OFF_META   = 8192;
    const size_t OFF_CURSOR = 24576;
    const size_t OFF_SORTED = 32768;
    const size_t NEED = OFF_SORTED + (size_t)BATCH * NA_ * 16;

    if (ws_size < NEED) {
        knn_brute_kernel<<<BATCH * (NB_ / 4), 256, 0, stream>>>(tfeat, tpos, spos, out);
        return;
    }

    char* ws = (char*)d_ws;
    int*    counts = (int*)(ws + OFF_COUNTS);
    int2*   meta   = (int2*)(ws + OFF_META);
    int*    cursor = (int*)(ws + OFF_CURSOR);
    float4* sorted = (float4*)(ws + OFF_SORTED);

    hipMemsetAsync(counts, 0, BATCH * NCELL * sizeof(int), stream);
    count_kernel<<<(BATCH * NA_ + 255) / 256, 256, 0, stream>>>(tpos, counts);
    scan_kernel<<<BATCH, NCELL, 0, stream>>>(counts, meta, cursor);
    scatter_kernel<<<(BATCH * NA_ + 255) / 256, 256, 0, stream>>>(tpos, cursor, sorted);
    knn_cells_kernel<<<BATCH * (NB_ / 4), 256, 0, stream>>>(tfeat, spos, meta, sorted, out);
}

// Round 4
// 78.754 us; speedup vs baseline: 9.2950x; 2.4478x over previous
//
#include <hip/hip_runtime.h>
#include <math.h>
#include <stdint.h>

#define K_NN   16
#define BATCH  2
#define NA_    16384
#define NB_    8192
#define CH     128
// coords are [z,y,x]: z in [0,64), y in [0,256), x in [0,256); cell edge 16
#define CZ     4
#define CY     16
#define CX     16
#define NCELL  (CZ*CY*CX)   // 1024
#define CSH    4
#define PADKEY 0xFFF00000u  // > any real key ((134019<<14)|16383 = 0x82E0BFFF)

// ---------------- grid build kernels ----------------

__device__ __forceinline__ int cell_of(float p0, float p1, float p2) {
    const int cz = ((int)p0) >> CSH;   // z/16 in [0,4)
    const int cy = ((int)p1) >> CSH;   // y/16 in [0,16)
    const int cx = ((int)p2) >> CSH;   // x/16 in [0,16)
    return (cz * CY + cy) * CX + cx;
}

__global__ void count_kernel(const float* __restrict__ tpos, int* __restrict__ counts) {
    int i = blockIdx.x * 256 + threadIdx.x;
    if (i >= BATCH * NA_) return;
    int b = i / NA_;
    const float* tp = tpos + (size_t)i * 3;
    atomicAdd(&counts[b * NCELL + cell_of(tp[0], tp[1], tp[2])], 1);
}

__global__ void scan_kernel(const int* __restrict__ counts,
                            int2* __restrict__ meta, int* __restrict__ cursor) {
    __shared__ int s[NCELL];
    const int b = blockIdx.x, t = threadIdx.x;
    int c = counts[b * NCELL + t];
    s[t] = c;
    __syncthreads();
    for (int off = 1; off < NCELL; off <<= 1) {
        int u = (t >= off) ? s[t - off] : 0;
        __syncthreads();
        s[t] += u;
        __syncthreads();
    }
    int excl = s[t] - c;
    meta[b * NCELL + t]   = make_int2(excl, c);
    cursor[b * NCELL + t] = excl;
}

__global__ void scatter_kernel(const float* __restrict__ tpos,
                               int* __restrict__ cursor, float4* __restrict__ sorted) {
    int i = blockIdx.x * 256 + threadIdx.x;
    if (i >= BATCH * NA_) return;
    int b = i / NA_, p = i % NA_;
    const float* tp = tpos + (size_t)i * 3;
    float p0 = tp[0], p1 = tp[1], p2 = tp[2];
    int cell = cell_of(p0, p1, p2);
    int pos = atomicAdd(&cursor[b * NCELL + cell], 1);
    sorted[(size_t)b * NA_ + pos] = make_float4(p0, p1, p2, __int_as_float(p));
}

// ---------------- merge: extract 16 smallest keys across the wave ----------------
// keys unique (idx embedded); pads > all real keys. sel[] lands wave-uniform (SGPR).

template<int NS>
__device__ __forceinline__ void merge_extract(uint32_t (&k)[NS], uint32_t (&sel)[K_NN]) {
    uint32_t m = k[0];
#pragma unroll
    for (int j = 1; j < NS; ++j) m = min(m, k[j]);
#pragma unroll
    for (int r = 0; r < K_NN; ++r) {
        uint32_t v = m;
#pragma unroll
        for (int off = 32; off > 0; off >>= 1)
            v = min(v, (uint32_t)__shfl_xor((int)v, off));
        sel[r] = (uint32_t)__builtin_amdgcn_readfirstlane((int)v);
        if (m == v) {                       // unique winner lane (real keys unique)
#pragma unroll
            for (int j = 0; j < NS; ++j) k[j] = (k[j] == v) ? 0xFFFFFFFFu : k[j];
            m = k[0];
#pragma unroll
            for (int j = 1; j < NS; ++j) m = min(m, k[j]);
        }
    }
}

// ---------------- main KNN + aggregation ----------------

__global__ __launch_bounds__(256) void knn_cells_kernel(
    const float* __restrict__ tfeat,   // [B, NA, C]
    const float* __restrict__ spos,    // [B, NB, 3]
    const int2*  __restrict__ meta,    // [B, NCELL] (start, count)
    const float4* __restrict__ sorted, // [B, NA] (z,y,x,idx-bits)
    float* __restrict__ out)           // [B, NB, C]
{
    const int tid  = threadIdx.x;
    const int lane = tid & 63;
    const int wave = tid >> 6;

    const int bpb = NB_ / 4;
    const int b = blockIdx.x / bpb;
    const int n = (blockIdx.x % bpb) * 4 + wave;

    const float* sp = spos + ((size_t)b * NB_ + n) * 3;
    const float s0 = sp[0], s1 = sp[1], s2 = sp[2];     // z, y, x
    const int scz = __builtin_amdgcn_readfirstlane(((int)s0) >> CSH);
    const int scy = __builtin_amdgcn_readfirstlane(((int)s1) >> CSH);
    const int scx = __builtin_amdgcn_readfirstlane(((int)s2) >> CSH);

    int rcov = max(max(scx, CX - 1 - scx), max(scy, CY - 1 - scy));
    rcov = max(rcov, max(scz, CZ - 1 - scz));

    const int2*   mb = meta   + (size_t)b * NCELL;
    const float4* sb = sorted + (size_t)b * NA_;

    // ---- 9 contiguous row-ranges of the 3x3x3 box (wave-uniform scalars) ----
    int rstart[9], rlen[9];
    const int cxlo = max(scx - 1, 0), cxhi = min(scx + 1, CX - 1);
    int nov = 0; bool fast = true;
#pragma unroll
    for (int kk = 0; kk < 9; ++kk) {
        const int cz = scz + kk / 3 - 1, cy = scy + kk % 3 - 1;
        int st = 0, ln = 0;
        if ((unsigned)cz < CZ && (unsigned)cy < CY) {
            const int rowb = (cz * CY + cy) * CX;
            const int2 mlo = mb[rowb + cxlo];
            const int2 mhi = mb[rowb + cxhi];
            st = mlo.x; ln = mhi.x + mhi.y - mlo.x;
        }
        rstart[kk] = st; rlen[kk] = ln;
        if (ln > 64) ++nov;
        if (ln > 128) fast = false;
    }
    if (nov > 3) fast = false;

    uint32_t sel[K_NN];

    for (int r = 1;; ++r) {
        if (r == 1 && fast) {
            // ---------- slotted fast path: no selection during scan ----------
            uint32_t key[12];
#pragma unroll
            for (int j = 0; j < 12; ++j) key[j] = PADKEY + j;
            int oc = 9;                                // next overflow slot (uniform)
#pragma unroll
            for (int kk = 0; kk < 9; ++kk) {
                if (rlen[kk] > 0) {
                    const bool act = lane < rlen[kk];
                    const int a = rstart[kk] + (act ? lane : 0);
                    const float4 p = sb[a];
                    const float d0 = s0 - p.x, d1 = s1 - p.y, d2c = s2 - p.z;
                    const float d2 = d0 * d0 + d1 * d1 + d2c * d2c;
                    const uint32_t kv = ((uint32_t)d2 << 14) | (uint32_t)__float_as_int(p.w);
                    key[kk] = act ? kv : key[kk];
                }
                if (rlen[kk] > 64) {                   // rare 2nd chunk (uniform branch)
                    const int j2 = 64 + lane;
                    const bool act = j2 < rlen[kk];
                    const int a = rstart[kk] + (act ? j2 : 0);
                    const float4 p = sb[a];
                    const float d0 = s0 - p.x, d1 = s1 - p.y, d2c = s2 - p.z;
                    const float d2 = d0 * d0 + d1 * d1 + d2c * d2c;
                    const uint32_t kv = ((uint32_t)d2 << 14) | (uint32_t)__float_as_int(p.w);
                    if (oc == 9)       key[9]  = act ? kv : key[9];
                    else if (oc == 10) key[10] = act ? kv : key[10];
                    else               key[11] = act ? kv : key[11];
                    ++oc;
                }
            }
            merge_extract<12>(key, sel);
        } else {
            // ---------- insert path: full box (r==1) or shell (r>1), seeded ----------
            uint32_t kl[K_NN];
#pragma unroll
            for (int j = 0; j < K_NN; ++j) kl[j] = PADKEY + 16 + j;
            if (r > 1) {
                uint32_t seed = 0xFFFFFFFFu;
#pragma unroll
                for (int j = 0; j < K_NN; ++j) if (lane == j) seed = sel[j];
                kl[0] = seed;
            }
            uint32_t curmax = kl[0];
#pragma unroll
            for (int j = 1; j < K_NN; ++j) curmax = max(curmax, kl[j]);

            for (int dz = -r; dz <= r; ++dz) {
                const int cz = scz + dz; if ((unsigned)cz >= CZ) continue;
                for (int dy = -r; dy <= r; ++dy) {
                    const int cy = scy + dy; if ((unsigned)cy >= CY) continue;
                    const int rowb = (cz * CY + cy) * CX;
                    const bool fullrow = (r == 1) || (max(abs(dz), abs(dy)) == r);
                    int xl[2], xh[2];
                    if (fullrow) {
                        xl[0] = max(scx - r, 0); xh[0] = min(scx + r, CX - 1);
                        xl[1] = 1; xh[1] = 0;
                    } else {
                        xl[0] = scx - r; xh[0] = scx - r;
                        xl[1] = scx + r; xh[1] = scx + r;
                        if (xl[0] < 0)      { xl[0] = 1; xh[0] = 0; }
                        if (xh[1] > CX - 1) { xl[1] = 1; xh[1] = 0; }
                    }
#pragma unroll
                    for (int q = 0; q < 2; ++q) {
                        if (xl[q] > xh[q]) continue;
                        const int2 mlo = mb[rowb + xl[q]];
                        const int2 mhi = mb[rowb + xh[q]];
                        const int st = mlo.x, ln = mhi.x + mhi.y - st;
                        for (int o = 0; o < ln; o += 64) {
                            const int j2 = o + lane;
                            const bool act = j2 < ln;
                            const int a = st + (act ? j2 : 0);
                            const float4 p = sb[a];
                            const float d0 = s0 - p.x, d1 = s1 - p.y, d2c = s2 - p.z;
                            const float d2 = d0 * d0 + d1 * d1 + d2c * d2c;
                            uint32_t kv = ((uint32_t)d2 << 14) | (uint32_t)__float_as_int(p.w);
                            kv = act ? kv : 0xFFFFFFFFu;
                            if (kv < curmax) {
#pragma unroll
                                for (int j = 0; j < K_NN; ++j)
                                    kl[j] = (kl[j] == curmax) ? kv : kl[j];
                                curmax = kl[0];
#pragma unroll
                                for (int j = 1; j < K_NN; ++j) curmax = max(curmax, kl[j]);
                            }
                        }
                    }
                }
            }
            merge_extract<K_NN>(kl, sel);
        }

        const uint32_t d16 = sel[K_NN - 1] >> 14;
        if (d16 <= (uint32_t)(256 * r * r) || r >= rcov) break;
    }

    // ---- weights + normalized feature aggregation ----
    float w[K_NN];
    float wsum = 0.f;
#pragma unroll
    for (int j = 0; j < K_NN; ++j) {
        w[j] = __expf(-0.5f * (float)(sel[j] >> 14));
        wsum += w[j];
    }
    const float inv = 1.0f / wsum;

    const float* fb = tfeat + (size_t)b * NA_ * CH;
    float acc0 = 0.f, acc1 = 0.f;
#pragma unroll
    for (int j = 0; j < K_NN; ++j) {
        const int idx = (int)(sel[j] & 16383u);
        const float ww = w[j] * inv;
        const float* f = fb + (size_t)idx * CH;
        acc0 += ww * f[lane];
        acc1 += ww * f[lane + 64];
    }

    float* o = out + ((size_t)b * NB_ + n) * CH;
    o[lane]      = acc0;
    o[lane + 64] = acc1;
}

// ---------------- launch ----------------

extern "C" void kernel_launch(void* const* d_in, const int* in_sizes, int n_in,
                              void* d_out, int out_size, void* d_ws, size_t ws_size,
                              hipStream_t stream) {
    const float* tfeat = (const float*)d_in[0];   // [B,NA,C]
    const float* tpos  = (const float*)d_in[1];   // [B,NA,3]
    const float* spos  = (const float*)d_in[2];   // [B,NB,3]
    float* out = (float*)d_out;                   // [B,NB,C]

    const size_t OFF_COUNTS = 0;
    const size_t OFF_META   = 8192;
    const size_t OFF_CURSOR = 24576;
    const size_t OFF_SORTED = 32768;
    const size_t NEED = OFF_SORTED + (size_t)BATCH * NA_ * 16;
    (void)NEED;

    char* ws = (char*)d_ws;
    int*    counts = (int*)(ws + OFF_COUNTS);
    int2*   meta   = (int2*)(ws + OFF_META);
    int*    cursor = (int*)(ws + OFF_CURSOR);
    float4* sorted = (float4*)(ws + OFF_SORTED);

    hipMemsetAsync(counts, 0, BATCH * NCELL * sizeof(int), stream);
    count_kernel<<<(BATCH * NA_ + 255) / 256, 256, 0, stream>>>(tpos, counts);
    scan_kernel<<<BATCH, NCELL, 0, stream>>>(counts, meta, cursor);
    scatter_kernel<<<(BATCH * NA_ + 255) / 256, 256, 0, stream>>>(tpos, cursor, sorted);
    knn_cells_kernel<<<BATCH * (NB_ / 4), 256, 0, stream>>>(tfeat, spos, meta, sorted, out);
}

// Round 5
// 63.445 us; speedup vs baseline: 11.5377x; 1.2413x over previous
//
#include <hip/hip_runtime.h>
#include <math.h>
#include <stdint.h>

#define K_NN   16
#define BATCH  2
#define NA_    16384
#define NB_    8192
#define CH     128
// coords are [z,y,x]: z in [0,64), y in [0,256), x in [0,256); cell edge 16
#define CZ     4
#define CY     16
#define CX     16
#define NCELL  (CZ*CY*CX)   // 1024
#define CSH    4
#define PADKEY 0xFFF00000u  // > any real key ((134019<<14)|16383 = 0x82E0BFFF)

// ---------------- grid build kernels ----------------

__device__ __forceinline__ int cell_of(float p0, float p1, float p2) {
    const int cz = ((int)p0) >> CSH;   // z/16 in [0,4)
    const int cy = ((int)p1) >> CSH;   // y/16 in [0,16)
    const int cx = ((int)p2) >> CSH;   // x/16 in [0,16)
    return (cz * CY + cy) * CX + cx;
}

__global__ void count_kernel(const float* __restrict__ tpos, int* __restrict__ counts) {
    int i = blockIdx.x * 256 + threadIdx.x;
    if (i >= BATCH * NA_) return;
    int b = i / NA_;
    const float* tp = tpos + (size_t)i * 3;
    atomicAdd(&counts[b * NCELL + cell_of(tp[0], tp[1], tp[2])], 1);
}

__global__ void scan_kernel(const int* __restrict__ counts,
                            int2* __restrict__ meta, int* __restrict__ cursor) {
    __shared__ int s[NCELL];
    const int b = blockIdx.x, t = threadIdx.x;
    int c = counts[b * NCELL + t];
    s[t] = c;
    __syncthreads();
    for (int off = 1; off < NCELL; off <<= 1) {
        int u = (t >= off) ? s[t - off] : 0;
        __syncthreads();
        s[t] += u;
        __syncthreads();
    }
    int excl = s[t] - c;
    meta[b * NCELL + t]   = make_int2(excl, c);
    cursor[b * NCELL + t] = excl;
}

__global__ void scatter_kernel(const float* __restrict__ tpos,
                               int* __restrict__ cursor, float4* __restrict__ sorted) {
    int i = blockIdx.x * 256 + threadIdx.x;
    if (i >= BATCH * NA_) return;
    int b = i / NA_, p = i % NA_;
    const float* tp = tpos + (size_t)i * 3;
    float p0 = tp[0], p1 = tp[1], p2 = tp[2];
    int cell = cell_of(p0, p1, p2);
    int pos = atomicAdd(&cursor[b * NCELL + cell], 1);
    sorted[(size_t)b * NA_ + pos] = make_float4(p0, p1, p2, __int_as_float(p));
}

// ---------------- fallback merge: extract 16 smallest keys across the wave ----------------

template<int NS>
__device__ __forceinline__ void merge_extract(uint32_t (&k)[NS], uint32_t (&sel)[K_NN]) {
    uint32_t m = k[0];
#pragma unroll
    for (int j = 1; j < NS; ++j) m = min(m, k[j]);
#pragma unroll
    for (int r = 0; r < K_NN; ++r) {
        uint32_t v = m;
#pragma unroll
        for (int off = 32; off > 0; off >>= 1)
            v = min(v, (uint32_t)__shfl_xor((int)v, off));
        sel[r] = (uint32_t)__builtin_amdgcn_readfirstlane((int)v);
        if (m == v) {
#pragma unroll
            for (int j = 0; j < NS; ++j) k[j] = (k[j] == v) ? 0xFFFFFFFFu : k[j];
            m = k[0];
#pragma unroll
            for (int j = 1; j < NS; ++j) m = min(m, k[j]);
        }
    }
}

// ---------------- main KNN + aggregation ----------------

__global__ __launch_bounds__(256) void knn_cells_kernel(
    const float* __restrict__ tfeat,   // [B, NA, C]
    const float* __restrict__ spos,    // [B, NB, 3]
    const int2*  __restrict__ meta,    // [B, NCELL] (start, count)
    const float4* __restrict__ sorted, // [B, NA] (z,y,x,idx-bits)
    float* __restrict__ out)           // [B, NB, C]
{
    __shared__ uint32_t sKeys[4][132];  // compacted candidates, wave-private
    __shared__ uint32_t sSel[4][16];    // rank-ordered winners, wave-private

    const int tid  = threadIdx.x;
    const int lane = tid & 63;
    const int wave = tid >> 6;

    const int bpb = NB_ / 4;
    const int b = blockIdx.x / bpb;
    const int n = (blockIdx.x % bpb) * 4 + wave;

    const float* sp = spos + ((size_t)b * NB_ + n) * 3;
    const float s0 = sp[0], s1 = sp[1], s2 = sp[2];     // z, y, x
    const int scz = __builtin_amdgcn_readfirstlane(((int)s0) >> CSH);
    const int scy = __builtin_amdgcn_readfirstlane(((int)s1) >> CSH);
    const int scx = __builtin_amdgcn_readfirstlane(((int)s2) >> CSH);

    int rcov = max(max(scx, CX - 1 - scx), max(scy, CY - 1 - scy));
    rcov = max(rcov, max(scz, CZ - 1 - scz));

    const int2*   mb = meta   + (size_t)b * NCELL;
    const float4* sb = sorted + (size_t)b * NA_;

    // ---- 9 contiguous row-ranges of the 3x3x3 box (wave-uniform scalars) ----
    int rstart[9], rlen[9];
    const int cxlo = max(scx - 1, 0), cxhi = min(scx + 1, CX - 1);
    int nov = 0; bool fast = true;
#pragma unroll
    for (int kk = 0; kk < 9; ++kk) {
        const int cz = scz + kk / 3 - 1, cy = scy + kk % 3 - 1;
        int st = 0, ln = 0;
        if ((unsigned)cz < CZ && (unsigned)cy < CY) {
            const int rowb = (cz * CY + cy) * CX;
            const int2 mlo = mb[rowb + cxlo];
            const int2 mhi = mb[rowb + cxhi];
            st = mlo.x; ln = mhi.x + mhi.y - mlo.x;
        }
        rstart[kk] = st; rlen[kk] = ln;
        if (ln > 64) ++nov;
        if (ln > 128) fast = false;
    }
    if (nov > 3) fast = false;

    uint32_t sel[K_NN];
    bool done = false;

    if (fast) {
        // ---------- slotted scan: no selection logic ----------
        uint32_t key[12];
#pragma unroll
        for (int j = 0; j < 12; ++j) key[j] = PADKEY + j;
        int oc = 9;
#pragma unroll
        for (int kk = 0; kk < 9; ++kk) {
            if (rlen[kk] > 0) {
                const bool act = lane < rlen[kk];
                const int a = rstart[kk] + (act ? lane : 0);
                const float4 p = sb[a];
                const float d0 = s0 - p.x, d1 = s1 - p.y, d2c = s2 - p.z;
                const float d2 = d0 * d0 + d1 * d1 + d2c * d2c;
                const uint32_t kv = ((uint32_t)d2 << 14) | (uint32_t)__float_as_int(p.w);
                key[kk] = act ? kv : key[kk];
            }
            if (rlen[kk] > 64) {
                const int j2 = 64 + lane;
                const bool act = j2 < rlen[kk];
                const int a = rstart[kk] + (act ? j2 : 0);
                const float4 p = sb[a];
                const float d0 = s0 - p.x, d1 = s1 - p.y, d2c = s2 - p.z;
                const float d2 = d0 * d0 + d1 * d1 + d2c * d2c;
                const uint32_t kv = ((uint32_t)d2 << 14) | (uint32_t)__float_as_int(p.w);
                if (oc == 9)       key[9]  = act ? kv : key[9];
                else if (oc == 10) key[10] = act ? kv : key[10];
                else               key[11] = act ? kv : key[11];
                ++oc;
            }
        }

        // ---------- two-tier census (packed) ----------
        const uint32_t KT1 = 169u << 14;   // d^2 < 169
        const uint32_t KT2 = 288u << 14;   // d^2 < 288 (ring-1 stop bound: outside box >= 289)
        uint32_t pc = 0;
#pragma unroll
        for (int j = 0; j < 12; ++j) {
            pc += (key[j] < KT1) ? 1u : 0u;
            pc += (key[j] < KT2) ? 0x10000u : 0u;
        }
#pragma unroll
        for (int off = 32; off > 0; off >>= 1)
            pc += (uint32_t)__shfl_xor((int)pc, off);
        const uint32_t c1 = (uint32_t)__builtin_amdgcn_readfirstlane((int)(pc & 0xFFFFu));
        const uint32_t c2 = (uint32_t)__builtin_amdgcn_readfirstlane((int)(pc >> 16));
        uint32_t keyT = 0;
        if (c1 >= K_NN) keyT = KT1;
        else if (c2 >= K_NN) keyT = KT2;

        if (keyT) {
            // ---------- ballot compaction into wave-private LDS ----------
            int nsel = 0;
#pragma unroll
            for (int j = 0; j < 12; ++j) {
                const bool pred = key[j] < keyT;
                const unsigned long long m = __ballot(pred);
                const int offp = __builtin_amdgcn_mbcnt_hi(
                    (uint32_t)(m >> 32), __builtin_amdgcn_mbcnt_lo((uint32_t)m, 0));
                const int dst = nsel + offp;
                if (pred && dst < 132) sKeys[wave][dst] = key[j];
                nsel += (int)__builtin_popcountll(m);
            }

            if (nsel >= K_NN && nsel <= 128) {
                const int padn = (4 - (nsel & 3)) & 3;
                if (lane < padn) sKeys[wave][nsel + lane] = 0xFFFFFFFFu;
                __threadfence_block();

                const uint32_t myk0 = (lane      < nsel) ? sKeys[wave][lane]      : 0xFFFFFFFFu;
                const uint32_t myk1 = (64 + lane < nsel) ? sKeys[wave][64 + lane] : 0xFFFFFFFFu;

                uint32_t r0 = 0, r1 = 0;
                const int nmax4 = (nsel + 3) & ~3;
                for (int j = 0; j < nmax4; j += 4) {
                    const uint4 k4 = *(const uint4*)&sKeys[wave][j];
                    r0 += (k4.x < myk0) + (k4.y < myk0) + (k4.z < myk0) + (k4.w < myk0);
                    r1 += (k4.x < myk1) + (k4.y < myk1) + (k4.z < myk1) + (k4.w < myk1);
                }
                if (r0 < K_NN) sSel[wave][r0] = myk0;
                if (r1 < K_NN) sSel[wave][r1] = myk1;
                __threadfence_block();

                const uint4 sA = *(const uint4*)&sSel[wave][0];
                const uint4 sB = *(const uint4*)&sSel[wave][4];
                const uint4 sC = *(const uint4*)&sSel[wave][8];
                const uint4 sD = *(const uint4*)&sSel[wave][12];
                sel[0]  = (uint32_t)__builtin_amdgcn_readfirstlane((int)sA.x);
                sel[1]  = (uint32_t)__builtin_amdgcn_readfirstlane((int)sA.y);
                sel[2]  = (uint32_t)__builtin_amdgcn_readfirstlane((int)sA.z);
                sel[3]  = (uint32_t)__builtin_amdgcn_readfirstlane((int)sA.w);
                sel[4]  = (uint32_t)__builtin_amdgcn_readfirstlane((int)sB.x);
                sel[5]  = (uint32_t)__builtin_amdgcn_readfirstlane((int)sB.y);
                sel[6]  = (uint32_t)__builtin_amdgcn_readfirstlane((int)sB.z);
                sel[7]  = (uint32_t)__builtin_amdgcn_readfirstlane((int)sB.w);
                sel[8]  = (uint32_t)__builtin_amdgcn_readfirstlane((int)sC.x);
                sel[9]  = (uint32_t)__builtin_amdgcn_readfirstlane((int)sC.y);
                sel[10] = (uint32_t)__builtin_amdgcn_readfirstlane((int)sC.z);
                sel[11] = (uint32_t)__builtin_amdgcn_readfirstlane((int)sC.w);
                sel[12] = (uint32_t)__builtin_amdgcn_readfirstlane((int)sD.x);
                sel[13] = (uint32_t)__builtin_amdgcn_readfirstlane((int)sD.y);
                sel[14] = (uint32_t)__builtin_amdgcn_readfirstlane((int)sD.z);
                sel[15] = (uint32_t)__builtin_amdgcn_readfirstlane((int)sD.w);
                done = true;
            }
        }
    }

    if (!done) {
        // ---------- exact ring loop with insert path ----------
        for (int r = 1;; ++r) {
            uint32_t kl[K_NN];
#pragma unroll
            for (int j = 0; j < K_NN; ++j) kl[j] = PADKEY + 16 + j;
            if (r > 1) {
                uint32_t seed = 0xFFFFFFFFu;
#pragma unroll
                for (int j = 0; j < K_NN; ++j) if (lane == j) seed = sel[j];
                kl[0] = seed;
            }
            uint32_t curmax = kl[0];
#pragma unroll
            for (int j = 1; j < K_NN; ++j) curmax = max(curmax, kl[j]);

            for (int dz = -r; dz <= r; ++dz) {
                const int cz = scz + dz; if ((unsigned)cz >= CZ) continue;
                for (int dy = -r; dy <= r; ++dy) {
                    const int cy = scy + dy; if ((unsigned)cy >= CY) continue;
                    const int rowb = (cz * CY + cy) * CX;
                    const bool fullrow = (r == 1) || (max(abs(dz), abs(dy)) == r);
                    int xl[2], xh[2];
                    if (fullrow) {
                        xl[0] = max(scx - r, 0); xh[0] = min(scx + r, CX - 1);
                        xl[1] = 1; xh[1] = 0;
                    } else {
                        xl[0] = scx - r; xh[0] = scx - r;
                        xl[1] = scx + r; xh[1] = scx + r;
                        if (xl[0] < 0)      { xl[0] = 1; xh[0] = 0; }
                        if (xh[1] > CX - 1) { xl[1] = 1; xh[1] = 0; }
                    }
#pragma unroll
                    for (int q = 0; q < 2; ++q) {
                        if (xl[q] > xh[q]) continue;
                        const int2 mlo = mb[rowb + xl[q]];
                        const int2 mhi = mb[rowb + xh[q]];
                        const int st = mlo.x, ln = mhi.x + mhi.y - st;
                        for (int o = 0; o < ln; o += 64) {
                            const int j2 = o + lane;
                            const bool act = j2 < ln;
                            const int a = st + (act ? j2 : 0);
                            const float4 p = sb[a];
                            const float d0 = s0 - p.x, d1 = s1 - p.y, d2c = s2 - p.z;
                            const float d2 = d0 * d0 + d1 * d1 + d2c * d2c;
                            uint32_t kv = ((uint32_t)d2 << 14) | (uint32_t)__float_as_int(p.w);
                            kv = act ? kv : 0xFFFFFFFFu;
                            if (kv < curmax) {
#pragma unroll
                                for (int j = 0; j < K_NN; ++j)
                                    kl[j] = (kl[j] == curmax) ? kv : kl[j];
                                curmax = kl[0];
#pragma unroll
                                for (int j = 1; j < K_NN; ++j) curmax = max(curmax, kl[j]);
                            }
                        }
                    }
                }
            }
            merge_extract<K_NN>(kl, sel);
            const uint32_t d16 = sel[K_NN - 1] >> 14;
            if (d16 <= (uint32_t)(256 * r * r) || r >= rcov) break;
        }
    }

    // ---- weights + normalized feature aggregation ----
    float w[K_NN];
    float wsum = 0.f;
#pragma unroll
    for (int j = 0; j < K_NN; ++j) {
        w[j] = __expf(-0.5f * (float)(sel[j] >> 14));
        wsum += w[j];
    }
    const float inv = 1.0f / wsum;

    const float* fb = tfeat + (size_t)b * NA_ * CH;
    float acc0 = 0.f, acc1 = 0.f;
#pragma unroll
    for (int j = 0; j < K_NN; ++j) {
        const int idx = (int)(sel[j] & 16383u);
        const float ww = w[j] * inv;
        const float* f = fb + (size_t)idx * CH;
        acc0 += ww * f[lane];
        acc1 += ww * f[lane + 64];
    }

    float* o = out + ((size_t)b * NB_ + n) * CH;
    o[lane]      = acc0;
    o[lane + 64] = acc1;
}

// ---------------- launch ----------------

extern "C" void kernel_launch(void* const* d_in, const int* in_sizes, int n_in,
                              void* d_out, int out_size, void* d_ws, size_t ws_size,
                              hipStream_t stream) {
    const float* tfeat = (const float*)d_in[0];   // [B,NA,C]
    const float* tpos  = (const float*)d_in[1];   // [B,NA,3]
    const float* spos  = (const float*)d_in[2];   // [B,NB,3]
    float* out = (float*)d_out;                   // [B,NB,C]

    const size_t OFF_COUNTS = 0;
    const size_t OFF_META   = 8192;
    const size_t OFF_CURSOR = 24576;
    const size_t OFF_SORTED = 32768;

    char* ws = (char*)d_ws;
    int*    counts = (int*)(ws + OFF_COUNTS);
    int2*   meta   = (int2*)(ws + OFF_META);
    int*    cursor = (int*)(ws + OFF_CURSOR);
    float4* sorted = (float4*)(ws + OFF_SORTED);

    hipMemsetAsync(counts, 0, BATCH * NCELL * sizeof(int), stream);
    count_kernel<<<(BATCH * NA_ + 255) / 256, 256, 0, stream>>>(tpos, counts);
    scan_kernel<<<BATCH, NCELL, 0, stream>>>(counts, meta, cursor);
    scatter_kernel<<<(BATCH * NA_ + 255) / 256, 256, 0, stream>>>(tpos, cursor, sorted);
    knn_cells_kernel<<<BATCH * (NB_ / 4), 256, 0, stream>>>(tfeat, spos, meta, sorted, out);
}